// Round 15
// baseline (48.345 us; speedup 1.0000x reference)
//
#include <hip/hip_runtime.h>
#include <math.h>

// Bit-exact float32 replication of the JAX-CPU reference chain.
#pragma clang fp contract(off)

#define BN 65536
#define SN 4
#define HH 128
#define WW 128

typedef float v4f __attribute__((ext_vector_type(4)));
typedef int v4i __attribute__((ext_vector_type(4)));
// Declared intrinsic (R7-validated): compiler tracks vmcnt precisely; OOB
// voffset lanes return 0, NO memory request.
__device__ v4f __llvm_buffer_load_v4f32(v4i rsrc, int voffset, int soffset,
                                        int aux) __asm("llvm.amdgcn.raw.buffer.load.v4f32");

// ---------- bit-exact prologue math (validated R1-R14) ----------
__device__ __forceinline__ void inv4(const float* P, float U[4][4]) {
#pragma clang fp contract(off)
    float a = P[10];
    float b = P[11];
    float ra = 1.0f / a;
    float l32 = P[14] * ra;
    float t = l32 * b;
    float u33 = 0.0f - t;
    float rf0 = 1.0f / P[0];
    float rf1 = 1.0f / P[5];
    float ru  = 1.0f / u33;
#pragma unroll
    for (int i = 0; i < 4; i++)
#pragma unroll
        for (int j = 0; j < 4; j++) U[i][j] = 0.0f;
    U[0][0] = rf0;
    U[1][1] = rf1;
    float x3c2 = (0.0f - l32) * ru;
    float y2c2 = fmaf(0.0f - b, x3c2, 1.0f);
    U[2][2] = y2c2 * ra;
    U[3][2] = x3c2;
    float x3c3 = ru;
    float y2c3 = 0.0f - (b * x3c3);
    U[2][3] = y2c3 * ra;
    U[3][3] = x3c3;
}

__device__ __forceinline__ void xform(const float M[4][4], float x, float y, float z,
                                      float& ox, float& oy, float& oz) {
#pragma clang fp contract(off)
    float o[4];
#pragma unroll
    for (int i = 0; i < 4; i++) {
        float acc = x * M[i][0];
        acc = acc + y * M[i][1];
        acc = acc + z * M[i][2];
        acc = acc + M[i][3];
        o[i] = acc;
    }
    ox = o[0] / o[3];
    oy = o[1] / o[3];
    oz = o[2] / o[3];
}

struct RS {
    float p0, p1, p2, d0, d1, d2;
    float y0, y1;          // RN(1/d0), RN(1/d1) — IEEE div, once per ray
    float fx, cy1;         // exact (cx+sx)/128 and 1-(cy+sy)/128
    float sxf, syf;        // sx/128, sy/128 (exact)
    float da, db, dc, hdz;
    int cx, cy, sx, sy, base, B, hoff, hk;
    bool still, testing, hit;
};

__device__ __forceinline__ void make_ray(RS& S, int r, const float* proj,
                                         const int* idxA, const int* xA, const int* yA,
                                         const float* dA, const float* dsA) {
#pragma clang fp contract(off)
    float P[4][4];
#pragma unroll
    for (int i = 0; i < 16; i++) ((float*)P)[i] = proj[i];
    float U[4][4];
    inv4(proj, U);
    int xi = xA[r], yi = yA[r];
    float t0 = ((float)xi + 0.5f) / 128.0f;
    float t1 = 1.0f - ((float)yi + 0.5f) / 128.0f;
    float ux = t0 * 2.0f - 1.0f;
    float uy = t1 * 2.0f - 1.0f;
    float ds = dsA[r] * 2.0f - 1.0f;
    float vx, vy, vz;
    xform(U, ux, uy, ds, vx, vy, vz);
    float ex = vx + dA[3 * r + 0] * 0.001f;
    float ey = vy + dA[3 * r + 1] * 0.001f;
    float ez = vz + dA[3 * r + 2] * 0.001f;
    float qx, qy, qz;
    xform(P, ex, ey, ez, qx, qy, qz);
    S.d0 = qx - ux;
    S.d1 = qy - uy;
    S.d2 = qz - ds;
    S.p0 = (ux + 1.0f) * 0.5f;
    S.p1 = (uy + 1.0f) * 0.5f;
    S.p2 = (ds + 1.0f) * 0.5f;
    S.sx = (S.d0 >= 0.0f) ? 1 : -1;
    S.sy = (S.d1 >= 0.0f) ? -1 : 1;
    S.cx = xi;
    S.cy = yi;
    // --- initial march (bit-identical to reference _march_next) ---
    {
        float nbx = (float)(S.cx + S.sx) / 128.0f;
        float nby = (float)(S.cy + S.sy) / 128.0f;
        float c1 = 1.0f - nby;
        float s0 = (nbx - S.p0) / S.d0;     // IEEE div (prologue only)
        float s1 = (c1 - S.p1) / S.d1;
        bool ty = s0 > s1;
        float t = ty ? s1 : s0;
        if (s1 != s1) t = s1;
        S.p0 = S.p0 + S.d0 * t;
        S.p1 = S.p1 + S.d1 * t;
        S.p2 = S.p2 + S.d2 * t;
        if (ty) S.cy += S.sy; else S.cx += S.sx;
    }
    S.y0 = 1.0f / S.d0;
    S.y1 = 1.0f / S.d1;
    S.fx  = (float)(S.cx + S.sx) / 128.0f;           // exact multiple of 1/128
    S.cy1 = 1.0f - (float)(S.cy + S.sy) / 128.0f;    // exact
    S.sxf = (float)S.sx * 0.0078125f;
    S.syf = (float)S.sy * 0.0078125f;
    S.da = dA[3 * r + 0]; S.db = dA[3 * r + 1]; S.dc = dA[3 * r + 2];
    S.base = idxA[r] * (HH * WW);
    S.B = 0; S.hoff = 0; S.hk = 0; S.hdz = 0.0f;
    S.still = true; S.testing = true; S.hit = false;
}

// Markstein correctly-rounded divide-by-invariant march (validated R4-R14).
#define MARCH { \
        float x0 = S.fx - S.p0; \
        float x1 = S.cy1 - S.p1; \
        float q0a = x0 * S.y0; \
        float rra = fmaf(-S.d0, q0a, x0); \
        float s0v = fmaf(rra, S.y0, q0a); \
        float q0b = x1 * S.y1; \
        float rrb = fmaf(-S.d1, q0b, x1); \
        float s1v = fmaf(rrb, S.y1, q0b); \
        bool ty = s0v > s1v; \
        float t = ty ? s1v : s0v; \
        t = (s1v != s1v) ? s1v : t; \
        float m0 = S.d0 * t; S.p0 = S.p0 + m0; \
        float m1 = S.d1 * t; S.p1 = S.p1 + m1; \
        float m2 = S.d2 * t; S.p2 = S.p2 + m2; \
        S.cx  += ty ? 0 : S.sx; \
        S.cy  += ty ? S.sy : 0; \
        S.fx  += ty ? 0.0f : S.sxf; \
        S.cy1 -= ty ? S.syf : 0.0f; }

#define BOXCHK(inow) { \
        bool ib = (S.p0 >= 0.0f) && (S.p0 <= 1.0f) && \
                  (S.p1 >= 0.0f) && (S.p1 <= 1.0f) && \
                  (S.p2 > 0.0f) && (S.p2 < 1.0f); \
        S.still = S.still && ib; \
        S.B = S.still ? ((inow) + 1) : S.B; }

// Packed per-cell float4 table: (z, n0, n1, n2). 1 MB, L2-resident.
// Also resets ws[0] (same-stream ordering: completes before march).
__global__ __launch_bounds__(256) void k_pack(const float* __restrict__ depth,
                                              const float* __restrict__ normal,
                                              float4* __restrict__ tab, int* ws) {
    int t = blockIdx.x * 256 + threadIdx.x;
    if (t == 0) ws[0] = 0;
    int s = t >> 14;
    int c = t & 16383;
    float4 v;
    v.x = depth[t];
    v.y = normal[s * 3 * HH * WW + c];
    v.z = normal[s * 3 * HH * WW + HH * WW + c];
    v.w = normal[s * 3 * HH * WW + 2 * HH * WW + c];
    tab[t] = v;
}

__global__ void k_zero(int* ws) { ws[0] = 0; }

// LDS-z march: all 4 depth planes staged in LDS as bf16 FLOORS (truncate =
// round-toward-zero for z>=0, so z_lo <= z and the LDS test pz>=z_lo is a
// SUPERSET of true candidates; ~0.4% false-candidate rate). Per state the
// only memory op is a CU-private ds_read_u16; the exact (z,n0,n1,n2) float4
// is buffer_loaded ONLY for candidates (~2/ray; OOB voffset otherwise -> no
// request). Exact hit test (pz>=z_exact && dot<=0) at consume -> bit-exact.
// Two-stage 8-lag pipeline: z-test at +8 (issues normal load), dot at +16.
__global__ __launch_bounds__(256, 1) void k_marchZ(const float* __restrict__ depth,
                                                   const float4* __restrict__ tab,
                                                   const int* idxA, const float* proj,
                                                   const int* xA, const int* yA,
                                                   const float* dA, const float* dsA,
                                                   float* out, int* ws) {
#pragma clang fp contract(off)
    extern __shared__ unsigned short zs[];   // 65536 x u16 = 128 KB
    // stage: top-16-bits of every depth value (coalesced float4 reads)
    for (int j = threadIdx.x; j < (SN * HH * WW) / 4; j += 256) {
        float4 dv = ((const float4*)depth)[j];
        ushort4 o;
        o.x = (unsigned short)(__float_as_uint(dv.x) >> 16);
        o.y = (unsigned short)(__float_as_uint(dv.y) >> 16);
        o.z = (unsigned short)(__float_as_uint(dv.z) >> 16);
        o.w = (unsigned short)(__float_as_uint(dv.w) >> 16);
        ((ushort4*)zs)[j] = o;
    }
    __syncthreads();

    int r = blockIdx.x * 256 + threadIdx.x;
    RS S;
    make_ray(S, r, proj, idxA, xA, yA, dA, dsA);

    v4i rsrc;
    {
        unsigned long long p = (unsigned long long)(const void*)tab;
        rsrc.x = (int)(p & 0xFFFFFFFFull);
        rsrc.y = (int)(p >> 32);            // stride=0, no swizzle
        rsrc.z = SN * HH * WW * 16;         // num_records = bytes
        rsrc.w = 0x00020000;                // raw untyped dword access
    }

    // z-slots (stage 1) and n-slots (stage 2), all statically named
#define DECL_Z(u) int zr##u = 0, zo##u = 0; float zq##u = 0.0f; bool zv##u = false;
#define DECL_N(u) v4f nld##u = {0,0,0,0}; int no##u = 0; float nq##u = 0.0f; bool nv##u = false;
    DECL_Z(0) DECL_Z(1) DECL_Z(2) DECL_Z(3) DECL_Z(4) DECL_Z(5) DECL_Z(6) DECL_Z(7)
    DECL_N(0) DECL_N(1) DECL_N(2) DECL_N(3) DECL_N(4) DECL_N(5) DECL_N(6) DECL_N(7)
#undef DECL_Z
#undef DECL_N

// stage-2 consume: exact hit test for state kcons (lag 16)
#define CONSUME_N(u, kcons) { \
        float t0 = S.da * nld##u.y; \
        float t1 = S.db * nld##u.z; \
        float t2 = S.dc * nld##u.w; \
        float dotv = (t0 + t1) + t2; \
        bool hc = nv##u && (nq##u >= nld##u.x) && (dotv <= 0.0f) && !S.hit; \
        S.hit = S.hit || hc; \
        S.hoff = hc ? no##u : S.hoff; \
        S.hk   = hc ? (kcons) : S.hk; \
        float dzn = nq##u - nld##u.x; \
        S.hdz  = hc ? dzn : S.hdz; \
        nv##u = false; }

// stage-1 consume: conservative z-test for state (lag 8); issues normal load
#define CONSUME_Z(u) { \
        float zf = __uint_as_float(((unsigned)zr##u) << 16); \
        bool cand = zv##u && (zq##u >= zf); \
        int voff = cand ? ((S.base + zo##u) << 4) : 0x40000000; \
        v4f vv = __llvm_buffer_load_v4f32(rsrc, voff, 0, 0); \
        nld##u = vv; nv##u = cand; nq##u = zq##u; no##u = zo##u; \
        zv##u = false; }

// stage-0 issue: testing update, LDS z read, record; then march
#define ISSUE_Z(u, inow) { \
        bool inpix = ((unsigned)S.cx < (unsigned)WW) && ((unsigned)S.cy < (unsigned)HH); \
        bool dead = (S.d2 <= 0.0f) && (S.p2 < 0.0f); \
        S.testing = S.testing && inpix && !S.hit && !dead; \
        int off = S.cy * WW + S.cx; \
        int zaddr = S.testing ? (S.base + off) : 0; \
        zr##u = zs[zaddr]; \
        zv##u = S.testing; zo##u = off; zq##u = S.p2; }

#define STEP(u, inow) { \
        CONSUME_N(u, (inow) - 16) \
        CONSUME_Z(u) \
        BOXCHK(inow) \
        ISSUE_Z(u, inow) \
        MARCH }

    int i = 0;
    while (i < 4096) {
        STEP(0, i)     STEP(1, i + 1) STEP(2, i + 2) STEP(3, i + 3)
        STEP(4, i + 4) STEP(5, i + 5) STEP(6, i + 6) STEP(7, i + 7)
        i += 8;
        if (!__any(S.testing)) break;
    }
    // drain: n-slots hold states i-16..i-9; z-slots hold i-8..i-1
    CONSUME_N(0, i - 16) CONSUME_N(1, i - 15) CONSUME_N(2, i - 14) CONSUME_N(3, i - 13)
    CONSUME_N(4, i - 12) CONSUME_N(5, i - 11) CONSUME_N(6, i - 10) CONSUME_N(7, i - 9)
    CONSUME_Z(0) CONSUME_Z(1) CONSUME_Z(2) CONSUME_Z(3)
    CONSUME_Z(4) CONSUME_Z(5) CONSUME_Z(6) CONSUME_Z(7)
    CONSUME_N(0, i - 8) CONSUME_N(1, i - 7) CONSUME_N(2, i - 6) CONSUME_N(3, i - 5)
    CONSUME_N(4, i - 4) CONSUME_N(5, i - 3) CONSUME_N(6, i - 2) CONSUME_N(7, i - 1)

    // Phase B: march-only, finish in-box prefix accounting
    while (i < 4096 && __any(S.still)) {
#pragma unroll
        for (int u = 0; u < 8; ++u) {
            BOXCHK(i + u)
            MARCH
        }
        i += 8;
    }
#undef STEP
#undef ISSUE_Z
#undef CONSUME_Z
#undef CONSUME_N

    int pk = S.hit ? (S.hoff | (1 << 14)) : 0;
    out[2 * r]      = (float)pk;
    out[2 * r + 1]  = (float)S.hk;
    out[3 * BN + r] = S.hdz;

    int Bm = S.B;
    for (int o = 32; o; o >>= 1) {
        int v = __shfl_down(Bm, o, 64);
        Bm = Bm > v ? Bm : v;
    }
    if ((threadIdx.x & 63) == 0) atomicMax(ws, Bm);
}

// Fallback (ws too small): R12 merged mono kernel, unpacked loads.
__global__ __launch_bounds__(256, 1) void k_march_mono(const float* __restrict__ depth,
                                                       const float* __restrict__ normal,
                                                       const int* idxA, const float* proj,
                                                       const int* xA, const int* yA,
                                                       const float* dA, const float* dsA,
                                                       float* out, int* ws) {
#pragma clang fp contract(off)
    int r = blockIdx.x * 256 + threadIdx.x;
    RS S;
    make_ray(S, r, proj, idxA, xA, yA, dA, dsA);
    const float* dep = depth + S.base;
    const float* nrm = normal + 3 * S.base;
#define DECL_SLOT(u) \
    float z##u = 0.0f, a##u = 0.0f, b##u = 0.0f, c##u = 0.0f, q##u = 0.0f; \
    int o##u = 0; bool v##u = false;
    DECL_SLOT(0) DECL_SLOT(1) DECL_SLOT(2) DECL_SLOT(3)
    DECL_SLOT(4) DECL_SLOT(5) DECL_SLOT(6) DECL_SLOT(7)
#undef DECL_SLOT
#define CONSUME(u, kcons) { \
        float t0 = S.da * a##u; \
        float t1 = S.db * b##u; \
        float t2 = S.dc * c##u; \
        float dotv = (t0 + t1) + t2; \
        bool hc = v##u && (q##u >= z##u) && (dotv <= 0.0f) && !S.hit; \
        S.hit = S.hit || hc; \
        S.hoff = hc ? o##u : S.hoff; \
        S.hk   = hc ? (kcons) : S.hk; \
        float dzn = q##u - z##u; \
        S.hdz  = hc ? dzn : S.hdz; \
        v##u = false; }
#define STEPU(u, inow) { \
        CONSUME(u, (inow) - 8) \
        BOXCHK(inow) \
        { bool inpix = ((unsigned)S.cx < (unsigned)WW) && ((unsigned)S.cy < (unsigned)HH); \
          bool dead = (S.d2 <= 0.0f) && (S.p2 < 0.0f); \
          S.testing = S.testing && inpix && !S.hit && !dead; \
          int off = S.cy * WW + S.cx; \
          v##u = S.testing; o##u = off; q##u = S.p2; \
          if (S.testing) { \
              z##u = dep[off]; \
              a##u = nrm[off]; \
              b##u = nrm[HH * WW + off]; \
              c##u = nrm[2 * HH * WW + off]; \
          } } \
        MARCH }
    int i = 0;
    while (i < 4096) {
        STEPU(0, i)     STEPU(1, i + 1) STEPU(2, i + 2) STEPU(3, i + 3)
        STEPU(4, i + 4) STEPU(5, i + 5) STEPU(6, i + 6) STEPU(7, i + 7)
        i += 8;
        if (!__any(S.testing)) break;
    }
    CONSUME(0, i - 8) CONSUME(1, i - 7) CONSUME(2, i - 6) CONSUME(3, i - 5)
    CONSUME(4, i - 4) CONSUME(5, i - 3) CONSUME(6, i - 2) CONSUME(7, i - 1)
    while (i < 4096 && __any(S.still)) {
#pragma unroll
        for (int u = 0; u < 8; ++u) {
            BOXCHK(i + u)
            MARCH
        }
        i += 8;
    }
#undef STEPU
#undef CONSUME
    int pk = S.hit ? (S.hoff | (1 << 14)) : 0;
    out[2 * r]      = (float)pk;
    out[2 * r + 1]  = (float)S.hk;
    out[3 * BN + r] = S.hdz;
    int Bm = S.B;
    for (int o = 32; o; o >>= 1) {
        int v = __shfl_down(Bm, o, 64);
        Bm = Bm > v ? Bm : v;
    }
    if ((threadIdx.x & 63) == 0) atomicMax(ws, Bm);
}

// Finalize: hit valid iff first-hit state index k < N (global trip count).
__global__ __launch_bounds__(256) void k_final(float* out, const int* ws) {
    int r = blockIdx.x * 256 + threadIdx.x;
    int N = ws[0];
    int pk = (int)out[2 * r];
    int k  = (int)out[2 * r + 1];
    float dzv = out[3 * BN + r];
    bool hit = (pk >> 14) & 1;
    bool ok = hit && (k < N);
    int rx = pk & 127, ry = (pk >> 7) & 127;
    out[2 * r]      = ok ? (float)rx : 0.0f;
    out[2 * r + 1]  = ok ? (float)ry : 0.0f;
    out[2 * BN + r] = ok ? 1.0f : 0.0f;
    out[3 * BN + r] = ok ? dzv : 0.0f;
}

extern "C" void kernel_launch(void* const* d_in, const int* in_sizes, int n_in,
                              void* d_out, int out_size, void* d_ws, size_t ws_size,
                              hipStream_t stream) {
    const float* depth = (const float*)d_in[0];
    const float* normal = (const float*)d_in[1];
    const int* indices = (const int*)d_in[2];
    const float* proj = (const float*)d_in[3];
    const int* x = (const int*)d_in[4];
    const int* y = (const int*)d_in[5];
    const float* d = (const float*)d_in[6];
    const float* ds = (const float*)d_in[7];
    float* out = (float*)d_out;
    int* ws = (int*)d_ws;

    const size_t tab_off = 64;
    const size_t need = tab_off + (size_t)SN * HH * WW * 16;
    float4* tab = (float4*)((char*)d_ws + tab_off);
    const int lds_bytes = SN * HH * WW * 2;   // 128 KB

    // allow 128 KB dynamic LDS (idempotent; not a stream op -> capture-safe)
    static bool attr_done = false;
    if (!attr_done) {
        hipFuncSetAttribute((const void*)k_marchZ,
                            hipFuncAttributeMaxDynamicSharedMemorySize, lds_bytes);
        attr_done = true;
    }

    if (ws_size >= need) {   // host-uniform: graph-capture safe
        k_pack<<<(SN * HH * WW) / 256, 256, 0, stream>>>(depth, normal, tab, ws);
        k_marchZ<<<BN / 256, 256, lds_bytes, stream>>>(depth, tab, indices, proj,
                                                       x, y, d, ds, out, ws);
    } else {
        k_zero<<<1, 1, 0, stream>>>(ws);
        k_march_mono<<<BN / 256, 256, 0, stream>>>(depth, normal, indices, proj,
                                                   x, y, d, ds, out, ws);
    }
    k_final<<<BN / 256, 256, 0, stream>>>(out, ws);
}

// Round 18
// 43.630 us; speedup vs baseline: 1.1081x; 1.1081x over previous
//
#include <hip/hip_runtime.h>
#include <math.h>

// Bit-exact float32 replication of the JAX-CPU reference chain.
#pragma clang fp contract(off)

#define BN 65536
#define SN 4
#define HH 128
#define WW 128

typedef float v4f __attribute__((ext_vector_type(4)));
typedef int v4i __attribute__((ext_vector_type(4)));
// Declared intrinsic (R7-validated): compiler tracks vmcnt precisely; OOB
// voffset lanes return 0, NO memory request.
__device__ v4f __llvm_buffer_load_v4f32(v4i rsrc, int voffset, int soffset,
                                        int aux) __asm("llvm.amdgcn.raw.buffer.load.v4f32");

// ---------- bit-exact prologue math (validated R1-R15) ----------
__device__ __forceinline__ void inv4(const float* P, float U[4][4]) {
#pragma clang fp contract(off)
    float a = P[10];
    float b = P[11];
    float ra = 1.0f / a;
    float l32 = P[14] * ra;
    float t = l32 * b;
    float u33 = 0.0f - t;
    float rf0 = 1.0f / P[0];
    float rf1 = 1.0f / P[5];
    float ru  = 1.0f / u33;
#pragma unroll
    for (int i = 0; i < 4; i++)
#pragma unroll
        for (int j = 0; j < 4; j++) U[i][j] = 0.0f;
    U[0][0] = rf0;
    U[1][1] = rf1;
    float x3c2 = (0.0f - l32) * ru;
    float y2c2 = fmaf(0.0f - b, x3c2, 1.0f);
    U[2][2] = y2c2 * ra;
    U[3][2] = x3c2;
    float x3c3 = ru;
    float y2c3 = 0.0f - (b * x3c3);
    U[2][3] = y2c3 * ra;
    U[3][3] = x3c3;
}

__device__ __forceinline__ void xform(const float M[4][4], float x, float y, float z,
                                      float& ox, float& oy, float& oz) {
#pragma clang fp contract(off)
    float o[4];
#pragma unroll
    for (int i = 0; i < 4; i++) {
        float acc = x * M[i][0];
        acc = acc + y * M[i][1];
        acc = acc + z * M[i][2];
        acc = acc + M[i][3];
        o[i] = acc;
    }
    ox = o[0] / o[3];
    oy = o[1] / o[3];
    oz = o[2] / o[3];
}

struct RS {
    float p0, p1, p2, d0, d1, d2;
    float y0, y1;          // RN(1/d0), RN(1/d1) — IEEE div, once per ray
    float fx, cy1;         // exact (cx+sx)/128 and 1-(cy+sy)/128
    float sxf, syf;        // sx/128, sy/128 (exact)
    float da, db, dc, hdz;
    int cx, cy, sx, sy, base, B, hoff, hk;
    bool still, testing, hit;
};

__device__ __forceinline__ void make_ray(RS& S, int r, const float* proj,
                                         const int* idxA, const int* xA, const int* yA,
                                         const float* dA, const float* dsA) {
#pragma clang fp contract(off)
    float P[4][4];
#pragma unroll
    for (int i = 0; i < 16; i++) ((float*)P)[i] = proj[i];
    float U[4][4];
    inv4(proj, U);
    int xi = xA[r], yi = yA[r];
    float t0 = ((float)xi + 0.5f) / 128.0f;
    float t1 = 1.0f - ((float)yi + 0.5f) / 128.0f;
    float ux = t0 * 2.0f - 1.0f;
    float uy = t1 * 2.0f - 1.0f;
    float ds = dsA[r] * 2.0f - 1.0f;
    float vx, vy, vz;
    xform(U, ux, uy, ds, vx, vy, vz);
    float ex = vx + dA[3 * r + 0] * 0.001f;
    float ey = vy + dA[3 * r + 1] * 0.001f;
    float ez = vz + dA[3 * r + 2] * 0.001f;
    float qx, qy, qz;
    xform(P, ex, ey, ez, qx, qy, qz);
    S.d0 = qx - ux;
    S.d1 = qy - uy;
    S.d2 = qz - ds;
    S.p0 = (ux + 1.0f) * 0.5f;
    S.p1 = (uy + 1.0f) * 0.5f;
    S.p2 = (ds + 1.0f) * 0.5f;
    S.sx = (S.d0 >= 0.0f) ? 1 : -1;
    S.sy = (S.d1 >= 0.0f) ? -1 : 1;
    S.cx = xi;
    S.cy = yi;
    // --- initial march (bit-identical to reference _march_next) ---
    {
        float nbx = (float)(S.cx + S.sx) / 128.0f;
        float nby = (float)(S.cy + S.sy) / 128.0f;
        float c1 = 1.0f - nby;
        float s0 = (nbx - S.p0) / S.d0;     // IEEE div (prologue only)
        float s1 = (c1 - S.p1) / S.d1;
        bool ty = s0 > s1;
        float t = ty ? s1 : s0;
        if (s1 != s1) t = s1;
        S.p0 = S.p0 + S.d0 * t;
        S.p1 = S.p1 + S.d1 * t;
        S.p2 = S.p2 + S.d2 * t;
        if (ty) S.cy += S.sy; else S.cx += S.sx;
    }
    S.y0 = 1.0f / S.d0;
    S.y1 = 1.0f / S.d1;
    S.fx  = (float)(S.cx + S.sx) / 128.0f;           // exact multiple of 1/128
    S.cy1 = 1.0f - (float)(S.cy + S.sy) / 128.0f;    // exact
    S.sxf = (float)S.sx * 0.0078125f;
    S.syf = (float)S.sy * 0.0078125f;
    S.da = dA[3 * r + 0]; S.db = dA[3 * r + 1]; S.dc = dA[3 * r + 2];
    S.base = idxA[r] * (HH * WW);
    S.B = 0; S.hoff = 0; S.hk = 0; S.hdz = 0.0f;
    S.still = true; S.testing = true; S.hit = false;
}

// Packed per-cell float4 table: (z, n0, n1, n2). 1 MB, L2-resident.
// Also resets ws[0] (same-stream ordering: completes before k_march8).
__global__ __launch_bounds__(256) void k_pack(const float* __restrict__ depth,
                                              const float* __restrict__ normal,
                                              float4* __restrict__ tab, int* ws) {
    int t = blockIdx.x * 256 + threadIdx.x;
    if (t == 0) ws[0] = 0;
    int s = t >> 14;
    int c = t & 16383;
    float4 v;
    v.x = depth[t];
    v.y = normal[s * 3 * HH * WW + c];
    v.z = normal[s * 3 * HH * WW + HH * WW + c];
    v.w = normal[s * 3 * HH * WW + 2 * HH * WW + c];
    tab[t] = v;
}

__global__ void k_zero(int* ws) { ws[0] = 0; }

// R7/R11 structure + DEAD-RAY CUTOFF: a ray with d2<=0 whose pz has dropped
// below 0 can never satisfy pz >= z (z = uniform[0,1) >= 0, pz monotone
// non-increasing since DDA t >= 0) -> retire its lane from testing. These
// rays are the long-tail request generators; the kernel is chip-wide
// gather-work bound (R3-R12 evidence), so cutting their requests is the
// lever. Hit semantics provably unchanged. [R12 configuration: best passing,
// 43.7 us; restored after k_pc (R16/R17) failed correctness twice.]
template <bool PACKED>
__global__ __launch_bounds__(256, 1) void k_march8(const float* __restrict__ depth,
                                                   const float* __restrict__ normal,
                                                   const float4* __restrict__ tab,
                                                   const int* idxA, const float* proj,
                                                   const int* xA, const int* yA,
                                                   const float* dA, const float* dsA,
                                                   float* out, int* ws) {
#pragma clang fp contract(off)
    int r = blockIdx.x * 256 + threadIdx.x;
    RS S;
    make_ray(S, r, proj, idxA, xA, yA, dA, dsA);
    const float* dep = depth + S.base;
    const float* nrm = normal + 3 * S.base;

    v4i rsrc;
    {
        unsigned long long p = (unsigned long long)(const void*)tab;
        rsrc.x = (int)(p & 0xFFFFFFFFull);
        rsrc.y = (int)(p >> 32);            // stride=0, no swizzle
        rsrc.z = SN * HH * WW * 16;         // num_records = bytes
        rsrc.w = 0x00020000;                // raw untyped dword access
    }

#define DECL_SLOT(u) \
    float z##u = 0.0f, a##u = 0.0f, b##u = 0.0f, c##u = 0.0f, q##u = 0.0f; \
    int o##u = 0; bool v##u = false;
    DECL_SLOT(0) DECL_SLOT(1) DECL_SLOT(2) DECL_SLOT(3)
    DECL_SLOT(4) DECL_SLOT(5) DECL_SLOT(6) DECL_SLOT(7)
#undef DECL_SLOT

#define CONSUME(u, kcons) { \
        float t0 = S.da * a##u; \
        float t1 = S.db * b##u; \
        float t2 = S.dc * c##u; \
        float dotv = (t0 + t1) + t2; \
        bool hc = v##u && (q##u >= z##u) && (dotv <= 0.0f) && !S.hit; \
        S.hit = S.hit || hc; \
        S.hoff = hc ? o##u : S.hoff; \
        S.hk   = hc ? (kcons) : S.hk; \
        float dzn = q##u - z##u; \
        S.hdz  = hc ? dzn : S.hdz; \
        v##u = false; }

#define BOXCHK(inow) { \
        bool ib = (S.p0 >= 0.0f) && (S.p0 <= 1.0f) && \
                  (S.p1 >= 0.0f) && (S.p1 <= 1.0f) && \
                  (S.p2 > 0.0f) && (S.p2 < 1.0f); \
        S.still = S.still && ib; \
        S.B = S.still ? ((inow) + 1) : S.B; }

#define MARCH { /* Markstein correctly-rounded div-by-invariant (validated) */ \
        float x0 = S.fx - S.p0; \
        float x1 = S.cy1 - S.p1; \
        float q0a = x0 * S.y0; \
        float rra = fmaf(-S.d0, q0a, x0); \
        float s0v = fmaf(rra, S.y0, q0a); \
        float q0b = x1 * S.y1; \
        float rrb = fmaf(-S.d1, q0b, x1); \
        float s1v = fmaf(rrb, S.y1, q0b); \
        bool ty = s0v > s1v; \
        float t = ty ? s1v : s0v; \
        t = (s1v != s1v) ? s1v : t; \
        float m0 = S.d0 * t; S.p0 = S.p0 + m0; \
        float m1 = S.d1 * t; S.p1 = S.p1 + m1; \
        float m2 = S.d2 * t; S.p2 = S.p2 + m2; \
        S.cx  += ty ? 0 : S.sx; \
        S.cy  += ty ? S.sy : 0; \
        S.fx  += ty ? 0.0f : S.sxf; \
        S.cy1 -= ty ? S.syf : 0.0f; }

#define STEP(u, inow) { \
        CONSUME(u, (inow) - 8) \
        BOXCHK(inow) \
        { bool inpix = ((unsigned)S.cx < (unsigned)WW) && ((unsigned)S.cy < (unsigned)HH); \
          bool dead = (S.d2 <= 0.0f) && (S.p2 < 0.0f);   /* can never hit again */ \
          S.testing = S.testing && inpix && !S.hit && !dead; \
          int off = S.cy * WW + S.cx; \
          v##u = S.testing; o##u = off; q##u = S.p2; \
          if (PACKED) { \
              int voff = S.testing ? ((S.base + off) << 4) : 0x40000000; \
              v4f vv = __llvm_buffer_load_v4f32(rsrc, voff, 0, 0); \
              z##u = vv.x; a##u = vv.y; b##u = vv.z; c##u = vv.w; \
          } else if (S.testing) { \
              z##u = dep[off]; \
              a##u = nrm[off]; \
              b##u = nrm[HH * WW + off]; \
              c##u = nrm[2 * HH * WW + off]; \
          } } \
        MARCH \
        __builtin_amdgcn_sched_barrier(0); }

    int i = 0;
    // ---- Phase A: hit search (8-slot pipeline, OOB-gated requests) ----
    while (i < 4096) {
        STEP(0, i)     STEP(1, i + 1) STEP(2, i + 2) STEP(3, i + 3)
        STEP(4, i + 4) STEP(5, i + 5) STEP(6, i + 6) STEP(7, i + 7)
        i += 8;
        if (!__any(S.testing)) break;
    }
    // drain pending slots in state order (slot u holds state i-8+u)
    CONSUME(0, i - 8) CONSUME(1, i - 7) CONSUME(2, i - 6) CONSUME(3, i - 5)
    CONSUME(4, i - 4) CONSUME(5, i - 3) CONSUME(6, i - 2) CONSUME(7, i - 1)

    // ---- Phase B: march-only, finish in-box prefix accounting ----
    while (i < 4096 && __any(S.still)) {
#pragma unroll
        for (int u = 0; u < 8; ++u) {
            BOXCHK(i + u)
            MARCH
        }
        i += 8;
    }
#undef STEP
#undef MARCH
#undef BOXCHK
#undef CONSUME

    // record (hoff == (ry<<7)|rx since hits are always in-pixel)
    int pk = S.hit ? (S.hoff | (1 << 14)) : 0;
    out[2 * r]      = (float)pk;
    out[2 * r + 1]  = (float)S.hk;
    out[3 * BN + r] = S.hdz;

    // N = max over all rays of in-box prefix length
    int Bm = S.B;
    for (int o = 32; o; o >>= 1) {
        int v = __shfl_down(Bm, o, 64);
        Bm = Bm > v ? Bm : v;
    }
    if ((threadIdx.x & 63) == 0) atomicMax(ws, Bm);
}

// Finalize: hit valid iff first-hit state index k < N (global trip count).
__global__ __launch_bounds__(256) void k_final(float* out, const int* ws) {
    int r = blockIdx.x * 256 + threadIdx.x;
    int N = ws[0];
    int pk = (int)out[2 * r];
    int k  = (int)out[2 * r + 1];
    float dzv = out[3 * BN + r];
    bool hit = (pk >> 14) & 1;
    bool ok = hit && (k < N);
    int rx = pk & 127, ry = (pk >> 7) & 127;
    out[2 * r]      = ok ? (float)rx : 0.0f;
    out[2 * r + 1]  = ok ? (float)ry : 0.0f;
    out[2 * BN + r] = ok ? 1.0f : 0.0f;
    out[3 * BN + r] = ok ? dzv : 0.0f;
}

extern "C" void kernel_launch(void* const* d_in, const int* in_sizes, int n_in,
                              void* d_out, int out_size, void* d_ws, size_t ws_size,
                              hipStream_t stream) {
    const float* depth = (const float*)d_in[0];
    const float* normal = (const float*)d_in[1];
    const int* indices = (const int*)d_in[2];
    const float* proj = (const float*)d_in[3];
    const int* x = (const int*)d_in[4];
    const int* y = (const int*)d_in[5];
    const float* d = (const float*)d_in[6];
    const float* ds = (const float*)d_in[7];
    float* out = (float*)d_out;
    int* ws = (int*)d_ws;

    const size_t tab_off = 64;
    const size_t need = tab_off + (size_t)SN * HH * WW * 16;
    float4* tab = (float4*)((char*)d_ws + tab_off);

    if (ws_size >= need) {   // host-uniform: graph-capture safe
        k_pack<<<(SN * HH * WW) / 256, 256, 0, stream>>>(depth, normal, tab, ws);
        k_march8<true><<<BN / 256, 256, 0, stream>>>(depth, normal, tab, indices,
                                                     proj, x, y, d, ds, out, ws);
    } else {
        k_zero<<<1, 1, 0, stream>>>(ws);
        k_march8<false><<<BN / 256, 256, 0, stream>>>(depth, normal, tab, indices,
                                                      proj, x, y, d, ds, out, ws);
    }
    k_final<<<BN / 256, 256, 0, stream>>>(out, ws);
}